// Round 19
// baseline (93.258 us; speedup 1.0000x reference)
//
#include <hip/hip_runtime.h>
#include <hip/hip_bf16.h>

typedef _Float16 f16x8 __attribute__((ext_vector_type(8)));
typedef float f32x4 __attribute__((ext_vector_type(4)));

#define BM 128      // rows per block
#define NCHUNK 32   // 3072 / 96 ; chunk = 8 features = 96 K-halves
#define IN_F 256
#define OUT_F 256
#define KDIM 3072   // 256 * 12
// frag-order: one "group" = 512 halves = 64 lanes x 8 halves (1 KB)
// A (LDS): 8 rowblks x 3 fk = 24 groups ; B (global, reg-direct): 16 colblks x 3 fk
// W2F global layout = chunk-major frag order: chunk c -> 48 contiguous groups

static __device__ inline unsigned pack2(float a, float b) {
  union { _Float16 h[2]; unsigned u; } t;
  t.h[0] = (_Float16)a;
  t.h[1] = (_Float16)b;
  return t.u;
}

// W2F unit u (16B = 8 halves): c=u/3072, r=u%3072, bcb=r/192, r2=r%192,
// g=r2/64, lane=r2%64 ; col o = bcb*16+(lane&15), k8 = g*4+(lane>>4),
// k-halves = c*96 + k8*8 .. +7 ; k=i*12+m -> m<11: coeff[o][i][m], m==11: base_w[o][i]
__global__ __launch_bounds__(256) void prep_w(const float* __restrict__ coeff,
                                              const float* __restrict__ base_w,
                                              _Float16* __restrict__ W2F) {
  const int u   = blockIdx.x * 256 + threadIdx.x;   // 384*256 = 98304 units
  const int c   = u / 3072;
  const int r   = u % 3072;
  const int bcb = r / 192;
  const int r2  = r % 192;
  const int g   = r2 / 64;
  const int ln  = r2 % 64;
  const int o   = bcb * 16 + (ln & 15);
  const int k8  = g * 4 + (ln >> 4);
  const int kh0 = c * 96 + k8 * 8;
  _Float16 h[8];
  #pragma unroll
  for (int e = 0; e < 8; ++e) {
    const int k = kh0 + e;
    const int i = k / 12, m = k % 12;
    const float v = (m == 11) ? base_w[o * IN_F + i] : coeff[(o * IN_F + i) * 11 + m];
    h[e] = (_Float16)v;
  }
  *(f16x8*)&W2F[(size_t)u * 8] = *(const f16x8*)h;
}

__global__ __launch_bounds__(512, 2) void kan_fused(const float* __restrict__ x,
                                                    const float* __restrict__ gamma,
                                                    const float* __restrict__ beta,
                                                    const _Float16* __restrict__ W2F,
                                                    float* __restrict__ out) {
  __shared__ _Float16 A0[24 * 512], A1[24 * 512];   // 24 KB each
  __shared__ float mu_s[BM], rs_s[BM];

  const int tid  = threadIdx.x;
  const int lane = tid & 63;
  const int wid  = tid >> 6;          // 0..7
  const int row0 = blockIdx.x * BM;

  // ---- LayerNorm stats: one wave per row ----
  for (int rr = wid; rr < BM; rr += 8) {
    const float4 v = *(const float4*)(x + (size_t)(row0 + rr) * IN_F + lane * 4);
    float s  = v.x + v.y + v.z + v.w;
    float sq = v.x * v.x + v.y * v.y + v.z * v.z + v.w * v.w;
    #pragma unroll
    for (int off = 32; off >= 1; off >>= 1) {
      s  += __shfl_xor(s, off);
      sq += __shfl_xor(sq, off);
    }
    if (lane == 0) {
      const float mu  = s * (1.0f / 256.0f);
      const float var = sq * (1.0f / 256.0f) - mu * mu;
      mu_s[rr] = mu;
      rs_s[rr] = 1.0f / sqrtf(var + 1e-5f);
    }
  }
  __syncthreads();                    // stats visible

  // wave roles: wr = row half, wc = col group; each wave 64x64 output
  const int wr   = wid >> 2;          // 0..1
  const int wc   = wid & 3;           // 0..3
  const int lrow = lane & 15;

  f32x4 acc[4][4] = {};

  // producer map (lrow-fastest):
  const int plrow = tid & 15;
  const int pfq   = (tid >> 4) & 3;   // feature-pair within chunk
  const int prb   = tid >> 6;         // row block 0..7 (== wid)
  const int prow  = prb * 16 + plrow; // 0..127
  const float mu = mu_s[prow], rs = rs_s[prow];
  const float* xrow = x + (size_t)(row0 + prow) * IN_F + pfq * 2;
  const float* grow = gamma + pfq * 2;
  const float* brow = beta + pfq * 2;

  // producer dest offsets (halves), one per 8-half group k8 = pfq*3 + j
  int aoff0, aoff1, aoff2;
  {
    const int k80 = pfq * 3 + 0, k81 = pfq * 3 + 1, k82 = pfq * 3 + 2;
    aoff0 = (prb * 3 + (k80 >> 2)) * 512 + (k80 & 3) * 128 + plrow * 8;
    aoff1 = (prb * 3 + (k81 >> 2)) * 512 + (k81 & 3) * 128 + plrow * 8;
    aoff2 = (prb * 3 + (k82 >> 2)) * 512 + (k82 & 3) * 128 + plrow * 8;
  }

  // B direct from L2 into registers: group (wc*4+fn)*3+fk of chunk c,
  // per-lane addr = base + lane*16 (perfectly coalesced 1 KB per wave-load)
  const char* const wbsrc = (const char*)W2F + (size_t)wc * 12288 + (size_t)lane * 16;
  auto loadB = [&](int c, f16x8* bf) {
    const char* gb = wbsrc + (size_t)c * 49152;
    #pragma unroll
    for (int fk = 0; fk < 3; ++fk)
      #pragma unroll
      for (int fn = 0; fn < 4; ++fn)
        bf[fk * 4 + fn] = *(const f16x8*)(gb + (fn * 3 + fk) * 1024);
  };

  // two-stage register window-placement produce
  auto produce = [&](_Float16* buf, float2 xv, float2 gv, float2 bv) {
    unsigned R[12];
    #pragma unroll
    for (int q = 0; q < 2; ++q) {
      const float xr = q ? xv.y : xv.x;
      const float gq = q ? gv.y : gv.x;
      const float bq = q ? bv.y : bv.x;
      const float n  = (xr - mu) * rs * gq + bq;
      const float v  = (n + 1.75f) * 4.0f;      // knots t_j = -1.75 + 0.25*j
      const float fj = floorf(v);
      const float u  = v - fj;
      const float u2 = u * u, u3 = u2 * u;
      const float w0 = (1.0f / 6.0f) * (1.0f - 3.0f * u + 3.0f * u2 - u3);
      const float w1 = (1.0f / 6.0f) * (3.0f * u3 - 6.0f * u2 + 4.0f);
      const float w2 = (1.0f / 6.0f) * (-3.0f * u3 + 3.0f * u2 + 3.0f * u + 1.0f);
      const float w3 = (1.0f / 6.0f) * u3;
      const unsigned W0 = pack2(w0, w1);
      const unsigned W1 = pack2(w2, w3);
      const int p    = (int)fj - 3;             // window start half
      const bool odd = (p & 1);
      const unsigned v0 = odd ? (W0 << 16) : W0;
      const unsigned v1 = odd ? ((W0 >> 16) | (W1 << 16)) : W1;
      const unsigned v2 = odd ? (W1 >> 16) : 0u;
      const int s0 = (v >= 0.0f && v < 14.0f) ? (p >> 1) : 99;  // OOB -> all drop
      const int s1 = s0 + 1, s2 = s0 + 2;
      #pragma unroll
      for (int k = 0; k < 6; ++k) {
        unsigned r = (k == s0) ? v0 : 0u;
        r = (k == s1) ? v1 : r;
        r = (k == s2) ? v2 : r;
        R[q * 6 + k] = r;
      }
      const float sl = xr * __builtin_amdgcn_rcpf(1.0f + __expf(-xr));  // silu(raw x)
      // half 11 of the field = word 5 high half (also kills j=12/13 overhang)
      R[q * 6 + 5] = (R[q * 6 + 5] & 0x0000FFFFu) | pack2(0.0f, sl);
    }
    *(f16x8*)&buf[aoff0] = *(const f16x8*)&R[0];
    *(f16x8*)&buf[aoff1] = *(const f16x8*)&R[4];
    *(f16x8*)&buf[aoff2] = *(const f16x8*)&R[8];
  };

  auto domfma = [&](const _Float16* Ab, const f16x8* bf) {
    #pragma unroll
    for (int fk = 0; fk < 3; ++fk) {
      f16x8 a[4];
      #pragma unroll
      for (int fm = 0; fm < 4; ++fm)
        a[fm] = *(const f16x8*)&Ab[((wr * 4 + fm) * 3 + fk) * 512 + lane * 8];
      #pragma unroll
      for (int fm = 0; fm < 4; ++fm)
        #pragma unroll
        for (int fn = 0; fn < 4; ++fn)
          acc[fm][fn] = __builtin_amdgcn_mfma_f32_16x16x32_f16(a[fm], bf[fk * 4 + fn], acc[fm][fn], 0, 0, 0);
    }
  };

  // prologue: B(0)->regs; prefetch x/gamma/beta chunks 0,1; produce A(0)
  f16x8 bA[12], bB[12];
  loadB(0, bA);
  float2 xv0 = *(const float2*)(xrow);
  float2 gv0 = *(const float2*)(grow);
  float2 bv0 = *(const float2*)(brow);
  float2 xv1 = *(const float2*)(xrow + 8);
  float2 gv1 = *(const float2*)(grow + 8);
  float2 bv1 = *(const float2*)(brow + 8);
  produce(A0, xv0, gv0, bv0);
  __syncthreads();

  for (int c = 0; c < NCHUNK; c += 2) {
    const int cp2 = (c + 2 < NCHUNK) ? (c + 2) : (NCHUNK - 1);
    const int cp3 = (c + 3 < NCHUNK) ? (c + 3) : (NCHUNK - 1);
    // interval even: consume {A0,bA}=c ; load B(c+1)->bB ; produce A(c+1)->A1
    loadB(c + 1, bB);
    xv0 = *(const float2*)(xrow + cp2 * 8);
    gv0 = *(const float2*)(grow + cp2 * 8);
    bv0 = *(const float2*)(brow + cp2 * 8);
    if (wid & 1) { domfma(A0, bA); produce(A1, xv1, gv1, bv1); }
    else         { produce(A1, xv1, gv1, bv1); domfma(A0, bA); }
    __syncthreads();
    // interval odd: consume {A1,bB}=c+1 ; load B(c+2)->bA ; produce A(c+2)->A0
    loadB(cp2, bA);
    xv1 = *(const float2*)(xrow + cp3 * 8);
    gv1 = *(const float2*)(grow + cp3 * 8);
    bv1 = *(const float2*)(brow + cp3 * 8);
    if (wid & 1) { domfma(A1, bB); produce(A0, xv0, gv0, bv0); }
    else         { produce(A0, xv0, gv0, bv0); domfma(A1, bB); }
    __syncthreads();
  }

  // ---- epilogue: D lane layout col = lane&15, row = (lane>>4)*4 + r ----
  const int orow0 = row0 + wr * 64 + (lane >> 4) * 4;
  const int ocol0 = wc * 64 + lrow;
  #pragma unroll
  for (int fm = 0; fm < 4; ++fm)
    #pragma unroll
    for (int fn = 0; fn < 4; ++fn)
      #pragma unroll
      for (int r = 0; r < 4; ++r)
        out[(size_t)(orow0 + fm * 16 + r) * OUT_F + ocol0 + fn * 16] = acc[fm][fn][r];
}

extern "C" void kernel_launch(void* const* d_in, const int* in_sizes, int n_in,
                              void* d_out, int out_size, void* d_ws, size_t ws_size,
                              hipStream_t stream) {
  const float* x      = (const float*)d_in[0];
  const float* gamma  = (const float*)d_in[1];
  const float* beta   = (const float*)d_in[2];
  const float* coeff  = (const float*)d_in[3];
  const float* base_w = (const float*)d_in[4];
  float* out = (float*)d_out;
  _Float16* W2F = (_Float16*)d_ws;   // 1.5 MB workspace, chunk-frag-order

  prep_w<<<dim3(384), dim3(256), 0, stream>>>(coeff, base_w, W2F);
  kan_fused<<<dim3(32768 / BM), dim3(512), 0, stream>>>(x, gamma, beta, W2F, out);
}

// Round 20
// 86.424 us; speedup vs baseline: 1.0791x; 1.0791x over previous
//
#include <hip/hip_runtime.h>
#include <hip/hip_bf16.h>

typedef _Float16 f16x8 __attribute__((ext_vector_type(8)));
typedef float f32x4 __attribute__((ext_vector_type(4)));

#define BM 128      // rows per block
#define NCHUNK 32   // 3072 / 96 ; chunk = 8 features = 96 K-halves
#define IN_F 256
#define OUT_F 256
#define KDIM 3072   // 256 * 12
// frag-order: one "group" = 512 halves = 64 lanes x 8 halves (1 KB)
// A (LDS): 8 rowblks x 3 fk = 24 groups ; B: global reg-direct per interval
// W2F global layout = chunk-major frag order: chunk c -> 48 contiguous groups

static __device__ inline unsigned pack2(float a, float b) {
  union { _Float16 h[2]; unsigned u; } t;
  t.h[0] = (_Float16)a;
  t.h[1] = (_Float16)b;
  return t.u;
}

// W2F unit u (16B = 8 halves): c=u/3072, r=u%3072, bcb=r/192, r2=r%192,
// g=r2/64, lane=r2%64 ; col o = bcb*16+(lane&15), k8 = g*4+(lane>>4),
// k-halves = c*96 + k8*8 .. +7 ; k=i*12+m -> m<11: coeff[o][i][m], m==11: base_w[o][i]
__global__ __launch_bounds__(256) void prep_w(const float* __restrict__ coeff,
                                              const float* __restrict__ base_w,
                                              _Float16* __restrict__ W2F) {
  const int u   = blockIdx.x * 256 + threadIdx.x;   // 384*256 = 98304 units
  const int c   = u / 3072;
  const int r   = u % 3072;
  const int bcb = r / 192;
  const int r2  = r % 192;
  const int g   = r2 / 64;
  const int ln  = r2 % 64;
  const int o   = bcb * 16 + (ln & 15);
  const int k8  = g * 4 + (ln >> 4);
  const int kh0 = c * 96 + k8 * 8;
  _Float16 h[8];
  #pragma unroll
  for (int e = 0; e < 8; ++e) {
    const int k = kh0 + e;
    const int i = k / 12, m = k % 12;
    const float v = (m == 11) ? base_w[o * IN_F + i] : coeff[(o * IN_F + i) * 11 + m];
    h[e] = (_Float16)v;
  }
  *(f16x8*)&W2F[(size_t)u * 8] = *(const f16x8*)h;
}

__global__ __launch_bounds__(512, 2) void kan_fused(const float* __restrict__ x,
                                                    const float* __restrict__ gamma,
                                                    const float* __restrict__ beta,
                                                    const _Float16* __restrict__ W2F,
                                                    float* __restrict__ out) {
  __shared__ _Float16 A0[24 * 512], A1[24 * 512];   // 24 KB each
  __shared__ float mu_s[BM], rs_s[BM];

  const int tid  = threadIdx.x;
  const int lane = tid & 63;
  const int wid  = tid >> 6;          // 0..7
  const int row0 = blockIdx.x * BM;

  // ---- LayerNorm stats: one wave per row ----
  for (int rr = wid; rr < BM; rr += 8) {
    const float4 v = *(const float4*)(x + (size_t)(row0 + rr) * IN_F + lane * 4);
    float s  = v.x + v.y + v.z + v.w;
    float sq = v.x * v.x + v.y * v.y + v.z * v.z + v.w * v.w;
    #pragma unroll
    for (int off = 32; off >= 1; off >>= 1) {
      s  += __shfl_xor(s, off);
      sq += __shfl_xor(sq, off);
    }
    if (lane == 0) {
      const float mu  = s * (1.0f / 256.0f);
      const float var = sq * (1.0f / 256.0f) - mu * mu;
      mu_s[rr] = mu;
      rs_s[rr] = 1.0f / sqrtf(var + 1e-5f);
    }
  }
  __syncthreads();                    // stats visible

  // wave roles: wr = row half, wc = col group; each wave 64x64 output
  const int wr   = wid >> 2;          // 0..1
  const int wc   = wid & 3;           // 0..3
  const int lrow = lane & 15;

  f32x4 acc[4][4] = {};

  // producer map (lrow-fastest):
  const int plrow = tid & 15;
  const int pfq   = (tid >> 4) & 3;   // feature-pair within chunk
  const int prb   = tid >> 6;         // row block 0..7 (== wid)
  const int prow  = prb * 16 + plrow; // 0..127
  const float mu = mu_s[prow], rs = rs_s[prow];
  const float* xrow = x + (size_t)(row0 + prow) * IN_F + pfq * 2;
  const float* grow = gamma + pfq * 2;
  const float* brow = beta + pfq * 2;

  // producer dest offsets (halves), one per 8-half group k8 = pfq*3 + j
  int aoff0, aoff1, aoff2;
  {
    const int k80 = pfq * 3 + 0, k81 = pfq * 3 + 1, k82 = pfq * 3 + 2;
    aoff0 = (prb * 3 + (k80 >> 2)) * 512 + (k80 & 3) * 128 + plrow * 8;
    aoff1 = (prb * 3 + (k81 >> 2)) * 512 + (k81 & 3) * 128 + plrow * 8;
    aoff2 = (prb * 3 + (k82 >> 2)) * 512 + (k82 & 3) * 128 + plrow * 8;
  }

  // B direct from L2 into registers: group (wc*4+fn)*3+fk of chunk c,
  // per-lane addr = base + lane*16 (coalesced 1 KB per wave-load),
  // offsets are compile-time -> folded into the load instruction
  const char* const wbsrc = (const char*)W2F + (size_t)wc * 12288 + (size_t)lane * 16;
  auto loadB = [&](int c, f16x8* bf) {
    const char* gb = wbsrc + (size_t)c * 49152;
    #pragma unroll
    for (int fk = 0; fk < 3; ++fk)
      #pragma unroll
      for (int fn = 0; fn < 4; ++fn)
        bf[fk * 4 + fn] = *(const f16x8*)(gb + (fn * 3 + fk) * 1024);
  };

  // two-stage register window-placement produce
  auto produce = [&](_Float16* buf, float2 xv, float2 gv, float2 bv) {
    unsigned R[12];
    #pragma unroll
    for (int q = 0; q < 2; ++q) {
      const float xr = q ? xv.y : xv.x;
      const float gq = q ? gv.y : gv.x;
      const float bq = q ? bv.y : bv.x;
      const float n  = (xr - mu) * rs * gq + bq;
      const float v  = (n + 1.75f) * 4.0f;      // knots t_j = -1.75 + 0.25*j
      const float fj = floorf(v);
      const float u  = v - fj;
      const float u2 = u * u, u3 = u2 * u;
      const float w0 = (1.0f / 6.0f) * (1.0f - 3.0f * u + 3.0f * u2 - u3);
      const float w1 = (1.0f / 6.0f) * (3.0f * u3 - 6.0f * u2 + 4.0f);
      const float w2 = (1.0f / 6.0f) * (-3.0f * u3 + 3.0f * u2 + 3.0f * u + 1.0f);
      const float w3 = (1.0f / 6.0f) * u3;
      const unsigned W0 = pack2(w0, w1);
      const unsigned W1 = pack2(w2, w3);
      const int p    = (int)fj - 3;             // window start half
      const bool odd = (p & 1);
      const unsigned v0 = odd ? (W0 << 16) : W0;
      const unsigned v1 = odd ? ((W0 >> 16) | (W1 << 16)) : W1;
      const unsigned v2 = odd ? (W1 >> 16) : 0u;
      const int s0 = (v >= 0.0f && v < 14.0f) ? (p >> 1) : 99;  // OOB -> all drop
      const int s1 = s0 + 1, s2 = s0 + 2;
      #pragma unroll
      for (int k = 0; k < 6; ++k) {
        unsigned r = (k == s0) ? v0 : 0u;
        r = (k == s1) ? v1 : r;
        r = (k == s2) ? v2 : r;
        R[q * 6 + k] = r;
      }
      const float sl = xr * __builtin_amdgcn_rcpf(1.0f + __expf(-xr));  // silu(raw x)
      // half 11 of the field = word 5 high half (also kills j=12/13 overhang)
      R[q * 6 + 5] = (R[q * 6 + 5] & 0x0000FFFFu) | pack2(0.0f, sl);
    }
    *(f16x8*)&buf[aoff0] = *(const f16x8*)&R[0];
    *(f16x8*)&buf[aoff1] = *(const f16x8*)&R[4];
    *(f16x8*)&buf[aoff2] = *(const f16x8*)&R[8];
  };

  auto domfma = [&](const _Float16* Ab, const f16x8* bf) {
    #pragma unroll
    for (int fk = 0; fk < 3; ++fk) {
      f16x8 a[4];
      #pragma unroll
      for (int fm = 0; fm < 4; ++fm)
        a[fm] = *(const f16x8*)&Ab[((wr * 4 + fm) * 3 + fk) * 512 + lane * 8];
      #pragma unroll
      for (int fm = 0; fm < 4; ++fm)
        #pragma unroll
        for (int fn = 0; fn < 4; ++fn)
          acc[fm][fn] = __builtin_amdgcn_mfma_f32_16x16x32_f16(a[fm], bf[fk * 4 + fn], acc[fm][fn], 0, 0, 0);
    }
  };

  // prologue: prefetch x/gamma/beta chunks 0,1; produce A(0)
  float2 xv0 = *(const float2*)(xrow);
  float2 gv0 = *(const float2*)(grow);
  float2 bv0 = *(const float2*)(brow);
  float2 xv1 = *(const float2*)(xrow + 8);
  float2 gv1 = *(const float2*)(grow + 8);
  float2 bv1 = *(const float2*)(brow + 8);
  produce(A0, xv0, gv0, bv0);
  __syncthreads();

  for (int c = 0; c < NCHUNK; c += 2) {
    const int cp2 = (c + 2 < NCHUNK) ? (c + 2) : (NCHUNK - 1);
    const int cp3 = (c + 3 < NCHUNK) ? (c + 3) : (NCHUNK - 1);
    // interval even: consume {A0, B(c)} ; produce A(c+1)->A1
    {
      f16x8 bfa[12];
      loadB(c, bfa);
      xv0 = *(const float2*)(xrow + cp2 * 8);
      gv0 = *(const float2*)(grow + cp2 * 8);
      bv0 = *(const float2*)(brow + cp2 * 8);
      if (wid & 1) { domfma(A0, bfa); produce(A1, xv1, gv1, bv1); }
      else         { produce(A1, xv1, gv1, bv1); domfma(A0, bfa); }
      __syncthreads();
    }
    // interval odd: consume {A1, B(c+1)} ; produce A(c+2)->A0
    {
      f16x8 bfb[12];
      loadB(c + 1, bfb);
      xv1 = *(const float2*)(xrow + cp3 * 8);
      gv1 = *(const float2*)(grow + cp3 * 8);
      bv1 = *(const float2*)(brow + cp3 * 8);
      if (wid & 1) { domfma(A1, bfb); produce(A0, xv0, gv0, bv0); }
      else         { produce(A0, xv0, gv0, bv0); domfma(A1, bfb); }
      __syncthreads();
    }
  }

  // ---- epilogue: D lane layout col = lane&15, row = (lane>>4)*4 + r ----
  const int orow0 = row0 + wr * 64 + (lane >> 4) * 4;
  const int ocol0 = wc * 64 + lrow;
  #pragma unroll
  for (int fm = 0; fm < 4; ++fm)
    #pragma unroll
    for (int fn = 0; fn < 4; ++fn)
      #pragma unroll
      for (int r = 0; r < 4; ++r)
        out[(size_t)(orow0 + fm * 16 + r) * OUT_F + ocol0 + fn * 16] = acc[fm][fn][r];
}

extern "C" void kernel_launch(void* const* d_in, const int* in_sizes, int n_in,
                              void* d_out, int out_size, void* d_ws, size_t ws_size,
                              hipStream_t stream) {
  const float* x      = (const float*)d_in[0];
  const float* gamma  = (const float*)d_in[1];
  const float* beta   = (const float*)d_in[2];
  const float* coeff  = (const float*)d_in[3];
  const float* base_w = (const float*)d_in[4];
  float* out = (float*)d_out;
  _Float16* W2F = (_Float16*)d_ws;   // 1.5 MB workspace, chunk-frag-order

  prep_w<<<dim3(384), dim3(256), 0, stream>>>(coeff, base_w, W2F);
  kan_fused<<<dim3(32768 / BM), dim3(512), 0, stream>>>(x, gamma, beta, W2F, out);
}